// Round 1
// baseline (370.190 us; speedup 1.0000x reference)
//
#include <hip/hip_runtime.h>
#include <hip/hip_cooperative_groups.h>

// PillarMaxPooling: Linear(10->64,nobias) -> BN1d(eval,eps=1e-3) -> ReLU ->
// segment_max -> clamp0.
//
// R8 (262us): 4-kernel sort (hist/scan/padfill/split) + pool.  Pool = 83us
//   latency-bound (MfmaUtil 3.9, VALU 21, HBM 31%); sort stages ~175us.
// R9: (a) sort fused into ONE cooperative kernel: idx read once, rank from
//   phase-1 LDS-hist atomicAdd return (held in regs across grid.sync),
//   block base from the phase-1 global atomicAdd return (cursor round gone),
//   scan recomputed redundantly per-block in LDS (no 2nd sync, no cross-XCD
//   starts read; tots only ever touched by device-scope atomics -> coherent),
//   padfill gone (pool masks tail by real count from tots).
//   (b) pool processes 128 tokens/wave-iter: 2 token + 10 gather loads in
//   flight per lane (Little's law: was 5x8B -> ~2.5TB/s; double the window).

#define C_IN   10
#define C_OUT  64
#define BSHIFT 7
#define BPILL  128
#define MAXNBP 2048              // supports M <= ~258k
#define NREG   8
#define SBLK   256
#define SCHUNK 4096
#define PPT    (SCHUNK / SBLK)   // 16 points per thread
#define PBLK   512
#define SENT   (128u << 24)

typedef _Float16 half8 __attribute__((ext_vector_type(8)));
typedef float    f32x4 __attribute__((ext_vector_type(4)));

namespace cg = cooperative_groups;

// ---------- K1: fused counting sort (cooperative) ----------
// phase1: hist + per-point rank + per-(block,bucket) base via atomic returns
// grid.sync
// phase2: redundant per-block padded exclusive scan (block 0 also -> global)
// phase3: scatter 4B tokens
__global__ __launch_bounds__(SBLK, 4)
void k_sort(const int* __restrict__ idx, int* __restrict__ tots,
            int* __restrict__ starts, unsigned int* __restrict__ sorted,
            int P, int NBpad, int E) {
    __shared__ int lh[MAXNBP];
    __shared__ int sbase[MAXNBP];
    __shared__ int tmp[SBLK];
    const int t  = threadIdx.x;
    const int r0 = (blockIdx.x & (NREG - 1)) * NBpad;

    for (int b = t; b < NBpad; b += SBLK) lh[b] = 0;
    __syncthreads();

    const int base = blockIdx.x * SCHUNK;
    int mm[PPT], rk[PPT];
#pragma unroll
    for (int i = 0; i < PPT; ++i) {
        int p = base + i * SBLK + t;
        mm[i] = (p < P) ? idx[p] : -1;
        rk[i] = (mm[i] >= 0) ? atomicAdd(&lh[mm[i] >> BSHIFT], 1) : 0;
    }
    __syncthreads();

    int* trow = tots + r0;
    for (int b = t; b < NBpad; b += SBLK) {
        int h = lh[b];
        sbase[b] = h ? atomicAdd(&trow[b], h) : 0;   // base within (region,bucket)
    }

    cg::this_grid().sync();

    // ---- phase 2: redundant scan (tots written only by atomics -> coherent)
    const int C = (E + SBLK - 1) / SBLK;
    int my = 0;
    for (int j = 0; j < C; ++j) {
        int e = t * C + j;
        if (e < E) my += (tots[e] + 15) & ~15;
    }
    tmp[t] = my; __syncthreads();
#pragma unroll
    for (int off = 1; off < SBLK; off <<= 1) {
        int x = (t >= off) ? tmp[t - off] : 0;
        __syncthreads(); tmp[t] += x; __syncthreads();
    }
    int ex = tmp[t] - my;
    const bool wr = (blockIdx.x == 0);
    for (int j = 0; j < C; ++j) {
        int e = t * C + j;
        if (e < E) {
            if (wr) starts[e] = ex;                  // for k_pool (next kernel)
            int d = e - r0;
            if ((unsigned)d < (unsigned)NBpad) sbase[d] += ex;
            ex += (tots[e] + 15) & ~15;
        }
    }
    if (wr && t == SBLK - 1) starts[E] = ex;
    __syncthreads();

    // ---- phase 3: scatter tokens
#pragma unroll
    for (int i = 0; i < PPT; ++i) {
        if (mm[i] >= 0) {
            int p = base + i * SBLK + t;
            int b = mm[i] >> BSHIFT;
            sorted[sbase[b] + rk[i]] =
                (unsigned)p | ((unsigned)(mm[i] & (BPILL - 1)) << 24);
        }
    }
}

// ---------- K2: pool — 128-token iters, dual gather in flight, MFMA ----------
__global__ __launch_bounds__(PBLK, 8)
void k_pool(const float* __restrict__ gf,
            const unsigned int* __restrict__ sorted,
            const int* __restrict__ starts,
            const int* __restrict__ tots,
            const float* __restrict__ W,
            const float* __restrict__ gamma,
            const float* __restrict__ beta,
            const float* __restrict__ rmean,
            const float* __restrict__ rvar,
            float* __restrict__ out, int M, int NBpad) {
    __shared__ unsigned int acc[129 * 65];   // stride 65; row 128 = trash (SENT)
    const int t = threadIdx.x;
    const int lane = t & 63;
    const int wv = t >> 6;                   // wave == region 0..7
    const int n = lane & 15;
    const int q = lane >> 4;

    for (int i = t; i < 129 * 65; i += PBLK) acc[i] = 0u;

    // B fragments: W rows k>=10 zeroed -> A K-padding free
    half8 bfrag[4];
    float inv[4], bia[4];
#pragma unroll
    for (int tt = 0; tt < 4; ++tt) {
        int c = tt * 16 + n;
#pragma unroll
        for (int j = 0; j < 8; ++j) {
            int k = q * 8 + j;
            bfrag[tt][j] = (k < C_IN) ? (_Float16)W[k * C_OUT + c] : (_Float16)0.f;
        }
        float is = gamma[c] * rsqrtf(rvar[c] + 1e-3f);
        inv[tt] = is;
        bia[tt] = fmaf(-rmean[c], is, beta[c]);
    }
    __syncthreads();

    const int e  = wv * NBpad + blockIdx.x;  // this wave's (region,bucket) entry
    const int s0 = starts[e];
    const int s1 = s0 + tots[e];             // REAL end (no pads consumed)
    const float2* gf2 = (const float2*)gf;

    auto proc = [&](unsigned v, int u0, int u1, int u2, int u3, int u4, int ng) {
#pragma unroll
        for (int g = 0; g < 4; ++g) {
            if (g >= ng) break;              // wave-uniform
            const int sl = (g << 4) + n;     // source lane: point g*16+n
            int b0 = __shfl(u0, sl, 64);
            int b1 = __shfl(u1, sl, 64);
            int b2 = __shfl(u2, sl, 64);
            int b3 = __shfl(u3, sl, 64);
            int b4 = __shfl(u4, sl, 64);
            int4 a32;
            a32.x = (q == 0) ? b0 : ((q == 1) ? b4 : 0);
            a32.y = (q == 0) ? b1 : 0;
            a32.z = (q == 0) ? b2 : 0;
            a32.w = (q == 0) ? b3 : 0;
            half8 a = __builtin_bit_cast(half8, a32);
            f32x4 z = {0.f, 0.f, 0.f, 0.f};
            f32x4 d0 = __builtin_amdgcn_mfma_f32_16x16x32_f16(a, bfrag[0], z, 0, 0, 0);
            f32x4 d1 = __builtin_amdgcn_mfma_f32_16x16x32_f16(a, bfrag[1], z, 0, 0, 0);
            f32x4 d2 = __builtin_amdgcn_mfma_f32_16x16x32_f16(a, bfrag[2], z, 0, 0, 0);
            f32x4 d3 = __builtin_amdgcn_mfma_f32_16x16x32_f16(a, bfrag[3], z, 0, 0, 0);
#pragma unroll
            for (int r = 0; r < 4; ++r) {    // C row = 4q+r = point
                int pv = __shfl((int)v, (g << 4) + (q << 2) + r, 64);
                int abase = (int)(((unsigned)pv) >> 24) * 65 + n;   // ml row
                float h0 = fmaxf(fmaf(d0[r], inv[0], bia[0]), 0.f);
                float h1 = fmaxf(fmaf(d1[r], inv[1], bia[1]), 0.f);
                float h2 = fmaxf(fmaf(d2[r], inv[2], bia[2]), 0.f);
                float h3 = fmaxf(fmaf(d3[r], inv[3], bia[3]), 0.f);
                atomicMax(&acc[abase +  0], __float_as_uint(h0));
                atomicMax(&acc[abase + 16], __float_as_uint(h1));
                atomicMax(&acc[abase + 32], __float_as_uint(h2));
                atomicMax(&acc[abase + 48], __float_as_uint(h3));
            }
        }
    };

    for (int rb = s0; rb < s1; rb += 128) {
        // two 64-token halves: issue ALL loads (2 token + 10 gf) back-to-back
        unsigned va = (rb + lane < s1) ? sorted[rb + lane] : SENT;
        unsigned vb = (rb + 64 + lane < s1) ? sorted[rb + 64 + lane] : SENT;
        const float2* sa = gf2 + (size_t)(va & 0xFFFFFFu) * 5;
        const float2* sb = gf2 + (size_t)(vb & 0xFFFFFFu) * 5;
        float2 xa0 = sa[0], xa1 = sa[1], xa2 = sa[2], xa3 = sa[3], xa4 = sa[4];
        float2 xb0 = sb[0], xb1 = sb[1], xb2 = sb[2], xb3 = sb[3], xb4 = sb[4];
        int uA0 = __builtin_bit_cast(int, __builtin_amdgcn_cvt_pkrtz(xa0.x, xa0.y));
        int uA1 = __builtin_bit_cast(int, __builtin_amdgcn_cvt_pkrtz(xa1.x, xa1.y));
        int uA2 = __builtin_bit_cast(int, __builtin_amdgcn_cvt_pkrtz(xa2.x, xa2.y));
        int uA3 = __builtin_bit_cast(int, __builtin_amdgcn_cvt_pkrtz(xa3.x, xa3.y));
        int uA4 = __builtin_bit_cast(int, __builtin_amdgcn_cvt_pkrtz(xa4.x, xa4.y));
        int uB0 = __builtin_bit_cast(int, __builtin_amdgcn_cvt_pkrtz(xb0.x, xb0.y));
        int uB1 = __builtin_bit_cast(int, __builtin_amdgcn_cvt_pkrtz(xb1.x, xb1.y));
        int uB2 = __builtin_bit_cast(int, __builtin_amdgcn_cvt_pkrtz(xb2.x, xb2.y));
        int uB3 = __builtin_bit_cast(int, __builtin_amdgcn_cvt_pkrtz(xb3.x, xb3.y));
        int uB4 = __builtin_bit_cast(int, __builtin_amdgcn_cvt_pkrtz(xb4.x, xb4.y));
        __builtin_amdgcn_sched_barrier(0);   // pin loads/converts before compute

        proc(va, uA0, uA1, uA2, uA3, uA4, min(4, ((s1 - rb) + 15) >> 4));
        if (rb + 64 < s1)
            proc(vb, uB0, uB1, uB2, uB3, uB4, min(4, ((s1 - rb - 64) + 15) >> 4));
    }
    __syncthreads();

    // coalesced writeback of 128 pillars x 64 channels
    const int mbase = blockIdx.x * BPILL;
#pragma unroll
    for (int i = 0; i < (BPILL * C_OUT) / PBLK; ++i) {
        int wdx = i * PBLK + t;
        int row = wdx >> 6, c = wdx & 63;
        int m = mbase + row;
        if (m < M) out[(size_t)m * C_OUT + c] = __uint_as_float(acc[row * 65 + c]);
    }
}

extern "C" void kernel_launch(void* const* d_in, const int* in_sizes, int n_in,
                              void* d_out, int out_size, void* d_ws, size_t ws_size,
                              hipStream_t stream) {
    const float* gf    = (const float*)d_in[0];
    const int*   idx   = (const int*)  d_in[1];
    const float* W     = (const float*)d_in[3];
    const float* gamma = (const float*)d_in[4];
    const float* beta  = (const float*)d_in[5];
    const float* rmean = (const float*)d_in[6];
    const float* rvar  = (const float*)d_in[7];
    float*       out   = (float*)d_out;

    const int P  = in_sizes[0] / C_IN;
    const int M  = out_size / C_OUT;
    const int NB    = (M + BPILL - 1) >> BSHIFT;    // 1563 for M=200k
    const int NBpad = (NB + 32) & ~31;              // 1568
    const int E     = NREG * NBpad;                 // 12544 entries
    const int NSB   = (P + SCHUNK - 1) / SCHUNK;    // 489 (2 blocks/CU co-res)

    char* ws = (char*)d_ws;
    auto align256 = [](size_t x) { return (x + 255) & ~(size_t)255; };
    int* tots   = (int*)ws;  ws += align256((size_t)E * 4);
    int* starts = (int*)ws;  ws += align256((size_t)(E + 1) * 4);
    unsigned int* sorted = (unsigned int*)ws;       // P + 16*E u32 (~8.8 MB)

    hipMemsetAsync(tots, 0, (size_t)E * 4, stream);

    int Pv = P, NBpadv = NBpad, Ev = E;
    void* kargs[] = { (void*)&idx, (void*)&tots, (void*)&starts, (void*)&sorted,
                      (void*)&Pv, (void*)&NBpadv, (void*)&Ev };
    hipLaunchCooperativeKernel((void*)k_sort, dim3(NSB), dim3(SBLK),
                               kargs, 0, stream);

    k_pool<<<NB, PBLK, 0, stream>>>(gf, sorted, starts, tots, W, gamma, beta,
                                    rmean, rvar, out, M, NBpad);
}

// Round 2
// 282.907 us; speedup vs baseline: 1.3085x; 1.3085x over previous
//
#include <hip/hip_runtime.h>

// PillarMaxPooling: Linear(10->64,nobias) -> BN1d(eval,eps=1e-3) -> ReLU ->
// segment_max -> clamp0.
//
// R8 (262us): 4-kernel sort (hist/scan/padfill/split) + pool(83us, occ 67%).
// R9 (370us, REVERTED): dual-64 gather doubled per-XCD L2 reuse window ->
//   FETCH 155->231MB, pool 142us; cooperative fused sort also slower.
// R10: keep R8 dataflow & 64-token gather (L2 window is the constraint).
//   (a) pool: persistent blocks (grid=1024 = exact residency), buckets via
//       global atomic counter -> kills the 539-block ragged tail (occ 67%).
//   (b) sort: 6->4 launches. k_scan folded into k_split as a redundant
//       per-block LDS scan (tots is atomic-written, kernel boundary = safe);
//       k_padfill dropped (pool uses real counts from tots, SENT-masks tail);
//       k_split rank captured from hist atomicAdd return (one LDS round);
//       zero-based relative cursor shares the single memset with tots.

#define C_IN   10
#define C_OUT  64
#define BSHIFT 7
#define BPILL  128
#define MAXNBP 2048              // supports M <= ~258k
#define NREG   8
#define SBLK   256
#define SCHUNK 2048
#define PPT    (SCHUNK / SBLK)   // 8 points per thread
#define PBLK   512
#define SENT   (128u << 24)

typedef _Float16 half8 __attribute__((ext_vector_type(8)));
typedef float    f32x4 __attribute__((ext_vector_type(4)));

// ---------- K1: bucket histogram -> tots[region][bucket] ----------
__global__ __launch_bounds__(SBLK)
void k_hist(const int* __restrict__ idx, int* __restrict__ tots,
            int P, int NBpad) {
    __shared__ int lh[MAXNBP];
    const int t = threadIdx.x;
    for (int b = t; b < NBpad; b += SBLK) lh[b] = 0;
    __syncthreads();
    const int base = blockIdx.x * SCHUNK;
#pragma unroll
    for (int i = 0; i < PPT; ++i) {
        int p = base + i * SBLK + t;
        if (p < P) atomicAdd(&lh[idx[p] >> BSHIFT], 1);
    }
    __syncthreads();
    int* row = tots + (size_t)(blockIdx.x & (NREG - 1)) * NBpad;
    for (int b = t; b < NBpad; b += SBLK) {
        int h = lh[b];
        if (h) atomicAdd(&row[b], h);
    }
}

// ---------- K2: split — redundant scan + region-keyed reservation ----------
// phase1: LDS hist, rank from atomic return (regs)
// phase2: redundant padded exclusive scan of tots (block 0 -> global starts)
// phase3: reserve via zero-based cursor, scatter 4B tokens
__global__ __launch_bounds__(SBLK)
void k_split(const int* __restrict__ idx, const int* __restrict__ tots,
             int* __restrict__ cursor, int* __restrict__ starts,
             unsigned int* __restrict__ sorted, int P, int NBpad, int E) {
    __shared__ int lh[MAXNBP];
    __shared__ int sbase[MAXNBP];
    __shared__ int tmp[SBLK];
    const int t  = threadIdx.x;
    const int r0 = (blockIdx.x & (NREG - 1)) * NBpad;

    for (int b = t; b < NBpad; b += SBLK) lh[b] = 0;
    __syncthreads();

    const int base = blockIdx.x * SCHUNK;
    int mm[PPT], rk[PPT];
#pragma unroll
    for (int i = 0; i < PPT; ++i) {
        int p = base + i * SBLK + t;
        mm[i] = (p < P) ? idx[p] : -1;
        rk[i] = (mm[i] >= 0) ? atomicAdd(&lh[mm[i] >> BSHIFT], 1) : 0;
    }
    __syncthreads();

    // ---- redundant padded exclusive scan over E entries
    const int C = (E + SBLK - 1) / SBLK;
    int my = 0;
    for (int j = 0; j < C; ++j) {
        int e = t * C + j;
        if (e < E) my += (tots[e] + 15) & ~15;
    }
    tmp[t] = my; __syncthreads();
#pragma unroll
    for (int off = 1; off < SBLK; off <<= 1) {
        int x = (t >= off) ? tmp[t - off] : 0;
        __syncthreads(); tmp[t] += x; __syncthreads();
    }
    int ex = tmp[t] - my;
    const bool wr = (blockIdx.x == 0);
    for (int j = 0; j < C; ++j) {
        int e = t * C + j;
        if (e < E) {
            if (wr) starts[e] = ex;              // consumed by k_pool only
            int d = e - r0;
            if ((unsigned)d < (unsigned)NBpad) sbase[d] = ex;
            ex += (tots[e] + 15) & ~15;
        }
    }
    if (wr && t == SBLK - 1) starts[E] = ex;
    __syncthreads();

    // ---- reserve block's slice within each (region,bucket)
    for (int b = t; b < NBpad; b += SBLK) {
        int h = lh[b];
        if (h) sbase[b] += atomicAdd(&cursor[r0 + b], h);
    }
    __syncthreads();

    // ---- scatter tokens
#pragma unroll
    for (int i = 0; i < PPT; ++i) {
        if (mm[i] >= 0) {
            int p = base + i * SBLK + t;
            int b = mm[i] >> BSHIFT;
            sorted[sbase[b] + rk[i]] =
                (unsigned)p | ((unsigned)(mm[i] & (BPILL - 1)) << 24);
        }
    }
}

// ---------- K3: pool — persistent blocks, lane-per-point gather, MFMA -------
__global__ __launch_bounds__(PBLK, 8)
void k_pool(const float* __restrict__ gf,
            const unsigned int* __restrict__ sorted,
            const int* __restrict__ starts,
            const int* __restrict__ tots,
            int* __restrict__ ctr,
            const float* __restrict__ W,
            const float* __restrict__ gamma,
            const float* __restrict__ beta,
            const float* __restrict__ rmean,
            const float* __restrict__ rvar,
            float* __restrict__ out, int M, int NB, int NBpad) {
    __shared__ unsigned int acc[129 * 65];   // stride 65; row 128 = trash (SENT)
    __shared__ int sblk;
    const int t = threadIdx.x;
    const int lane = t & 63;
    const int wv = t >> 6;                   // wave == region 0..7
    const int n = lane & 15;
    const int q = lane >> 4;

    // B fragments: W rows k>=10 zeroed -> A K-padding free
    half8 bfrag[4];
    float inv[4], bia[4];
#pragma unroll
    for (int tt = 0; tt < 4; ++tt) {
        int c = tt * 16 + n;
#pragma unroll
        for (int j = 0; j < 8; ++j) {
            int k = q * 8 + j;
            bfrag[tt][j] = (k < C_IN) ? (_Float16)W[k * C_OUT + c] : (_Float16)0.f;
        }
        float is = gamma[c] * rsqrtf(rvar[c] + 1e-3f);
        inv[tt] = is;
        bia[tt] = fmaf(-rmean[c], is, beta[c]);
    }

    const float2* gf2 = (const float2*)gf;

    for (;;) {
        __syncthreads();                     // writeback readers done; sblk free
        if (t == 0) sblk = atomicAdd(ctr, 1);
        for (int i = t; i < 129 * 65; i += PBLK) acc[i] = 0u;
        __syncthreads();                     // sblk + zeroed acc visible
        const int blk = sblk;
        if (blk >= NB) break;

        const int e  = wv * NBpad + blk;     // this wave's (region,bucket)
        const int s0 = starts[e];
        const int s1 = s0 + tots[e];         // real end; tail SENT-masked

        for (int rb = s0; rb < s1; rb += 64) {
            // lane-per-point: full-wave 40B contiguous gather + packed cvt
            unsigned v = (rb + lane < s1) ? sorted[rb + lane] : SENT;
            const float2* src = gf2 + (size_t)(v & 0xFFFFFFu) * 5;
            float2 x0 = src[0], x1 = src[1], x2 = src[2], x3 = src[3], x4 = src[4];
            int u0 = __builtin_bit_cast(int, __builtin_amdgcn_cvt_pkrtz(x0.x, x0.y));
            int u1 = __builtin_bit_cast(int, __builtin_amdgcn_cvt_pkrtz(x1.x, x1.y));
            int u2 = __builtin_bit_cast(int, __builtin_amdgcn_cvt_pkrtz(x2.x, x2.y));
            int u3 = __builtin_bit_cast(int, __builtin_amdgcn_cvt_pkrtz(x3.x, x3.y));
            int u4 = __builtin_bit_cast(int, __builtin_amdgcn_cvt_pkrtz(x4.x, x4.y));

            const int ng = min(4, ((s1 - rb) + 15) >> 4);   // 16-groups left
#pragma unroll
            for (int g = 0; g < 4; ++g) {
                if (g >= ng) break;              // wave-uniform
                const int sl = (g << 4) + n;     // source lane: point g*16+n
                int b0 = __shfl(u0, sl, 64);
                int b1 = __shfl(u1, sl, 64);
                int b2 = __shfl(u2, sl, 64);
                int b3 = __shfl(u3, sl, 64);
                int b4 = __shfl(u4, sl, 64);
                int4 a32;
                a32.x = (q == 0) ? b0 : ((q == 1) ? b4 : 0);
                a32.y = (q == 0) ? b1 : 0;
                a32.z = (q == 0) ? b2 : 0;
                a32.w = (q == 0) ? b3 : 0;
                half8 a = __builtin_bit_cast(half8, a32);
                f32x4 z = {0.f, 0.f, 0.f, 0.f};
                f32x4 d0 = __builtin_amdgcn_mfma_f32_16x16x32_f16(a, bfrag[0], z, 0, 0, 0);
                f32x4 d1 = __builtin_amdgcn_mfma_f32_16x16x32_f16(a, bfrag[1], z, 0, 0, 0);
                f32x4 d2 = __builtin_amdgcn_mfma_f32_16x16x32_f16(a, bfrag[2], z, 0, 0, 0);
                f32x4 d3 = __builtin_amdgcn_mfma_f32_16x16x32_f16(a, bfrag[3], z, 0, 0, 0);
#pragma unroll
                for (int r = 0; r < 4; ++r) {    // C row = 4q+r = point
                    int pv = __shfl((int)v, (g << 4) + (q << 2) + r, 64);
                    int abase = (int)(((unsigned)pv) >> 24) * 65 + n;   // ml row
                    float h0 = fmaxf(fmaf(d0[r], inv[0], bia[0]), 0.f);
                    float h1 = fmaxf(fmaf(d1[r], inv[1], bia[1]), 0.f);
                    float h2 = fmaxf(fmaf(d2[r], inv[2], bia[2]), 0.f);
                    float h3 = fmaxf(fmaf(d3[r], inv[3], bia[3]), 0.f);
                    atomicMax(&acc[abase +  0], __float_as_uint(h0));
                    atomicMax(&acc[abase + 16], __float_as_uint(h1));
                    atomicMax(&acc[abase + 32], __float_as_uint(h2));
                    atomicMax(&acc[abase + 48], __float_as_uint(h3));
                }
            }
        }
        __syncthreads();

        // coalesced writeback of 128 pillars x 64 channels
        const int mbase = blk * BPILL;
#pragma unroll
        for (int i = 0; i < (BPILL * C_OUT) / PBLK; ++i) {
            int wdx = i * PBLK + t;
            int row = wdx >> 6, c = wdx & 63;
            int m = mbase + row;
            if (m < M) out[(size_t)m * C_OUT + c] = __uint_as_float(acc[row * 65 + c]);
        }
    }
}

extern "C" void kernel_launch(void* const* d_in, const int* in_sizes, int n_in,
                              void* d_out, int out_size, void* d_ws, size_t ws_size,
                              hipStream_t stream) {
    const float* gf    = (const float*)d_in[0];
    const int*   idx   = (const int*)  d_in[1];
    const float* W     = (const float*)d_in[3];
    const float* gamma = (const float*)d_in[4];
    const float* beta  = (const float*)d_in[5];
    const float* rmean = (const float*)d_in[6];
    const float* rvar  = (const float*)d_in[7];
    float*       out   = (float*)d_out;

    const int P  = in_sizes[0] / C_IN;
    const int M  = out_size / C_OUT;
    const int NB    = (M + BPILL - 1) >> BSHIFT;    // 1563 for M=200k
    const int NBpad = (NB + 32) & ~31;              // 1568
    const int E     = NREG * NBpad;                 // 12544 entries
    const int NSB   = (P + SCHUNK - 1) / SCHUNK;    // 977

    char* ws = (char*)d_ws;
    auto align256 = [](size_t x) { return (x + 255) & ~(size_t)255; };
    int* tots   = (int*)ws;  ws += align256((size_t)E * 4);
    int* cursor = (int*)ws;  ws += align256((size_t)E * 4);
    int* ctr    = (int*)ws;  ws += 256;
    int* starts = (int*)ws;  ws += align256((size_t)(E + 1) * 4);
    unsigned int* sorted = (unsigned int*)ws;       // P + 16*E u32 (~8.8 MB)

    // one memset covers tots + cursor + ctr (contiguous)
    hipMemsetAsync(tots, 0, (size_t)((char*)starts - (char*)tots), stream);

    k_hist <<<NSB, SBLK, 0, stream>>>(idx, tots, P, NBpad);
    k_split<<<NSB, SBLK, 0, stream>>>(idx, tots, cursor, starts, sorted,
                                      P, NBpad, E);

    const int NPB = NB < 1024 ? NB : 1024;          // exact residency, persistent
    k_pool <<<NPB, PBLK, 0, stream>>>(gf, sorted, starts, tots, ctr, W, gamma,
                                      beta, rmean, rvar, out, M, NB, NBpad);
}

// Round 3
// 215.811 us; speedup vs baseline: 1.7153x; 1.3109x over previous
//
#include <hip/hip_runtime.h>

// PillarMaxPooling: Linear(10->64,nobias) -> BN1d(eval,eps=1e-3) -> ReLU ->
// segment_max -> clamp0.
//
// R8 (262us): 4-kernel counting sort (hist/scan/padfill/split) + pool(83us).
// R9 (370us, REVERTED): 128-token gather window -> FETCH +76MB; coop sort slower.
// R10 (283us, REVERTED): persistent pool blocks -> FETCH+WRITE +85MB, 103us;
//   fused scan into split saved nothing (redundant scan ate the savings).
//   Lesson: R8's static-grid 64-token pool is the gather optimum; sort cost
//   is idx x2 + two LDS hist builds + 2.4M global atomics, NOT launch count.
// R11: kill the counting sort. Fixed-capacity (bucket,region) cells
//   (CAPR=512; cell mean ~160, max ~220 over 12.5k cells -> 22-sigma margin)
//   -> no scan, no padfill, no second pass: ONE scatter kernel. idx read
//   once, rank from LDS-hist atomic return, one global atomicAdd per
//   (block,bucket) reservation (~0.7M total, SCHUNK=4096), region-keyed
//   slices keep token lines XCD-local. Overflow -> direct-MLP atomicMax
//   fallback (never taken for bench input; pool then merges via atomicMax).
//   Pool = R8 structure exactly (static grid NB, 64-token iters), count from
//   cnt[] (SENT-masked tail, proven R10), base = (b*NREG+r)*CAPR.

#define C_IN   10
#define C_OUT  64
#define BSHIFT 7
#define BPILL  128
#define MAXNBP 2048              // supports M <= ~258k
#define NREG   8
#define SBLK   256
#define SCHUNK 4096
#define PPT    (SCHUNK / SBLK)   // 16 points per thread
#define PBLK   512
#define SENT   (128u << 24)

typedef _Float16 half8 __attribute__((ext_vector_type(8)));
typedef float    f32x4 __attribute__((ext_vector_type(4)));

// Overflow fallback: direct per-point MLP + device atomicMax on out.
// Never taken for the bench distribution (cap margin ~22 sigma); noinline
// keeps the hot scatter loop's register budget clean.
__device__ __attribute__((noinline))
void fallback_point(int p, int m, const float* gf, const float* W,
                    const float* gamma, const float* beta,
                    const float* rmean, const float* rvar,
                    float* out, int* ovf) {
    atomicExch(ovf, 1);
    const float* x = gf + (size_t)p * C_IN;
    unsigned* o = (unsigned*)out + (size_t)m * C_OUT;
#pragma clang loop unroll(disable)
    for (int c = 0; c < C_OUT; ++c) {
        float is = gamma[c] * rsqrtf(rvar[c] + 1e-3f);
        float bb = fmaf(-rmean[c], is, beta[c]);
        float d = 0.f;
        for (int k = 0; k < C_IN; ++k) d = fmaf(x[k], W[k * C_OUT + c], d);
        atomicMax(o + c, __float_as_uint(fmaxf(fmaf(d, is, bb), 0.f)));
    }
}

// ---------- K1: one-pass scatter into fixed-capacity (bucket,region) cells --
// phase1: LDS hist, per-point rank from atomic return (held in regs)
// phase2: one global atomicAdd per (block, nonempty bucket) -> cell base
// phase3: scatter 4B tokens to sorted[(b*NREG+r)*CAPR + slot]
__global__ __launch_bounds__(SBLK)
void k_scatter(const int* __restrict__ idx,
               const float* __restrict__ gf,
               const float* __restrict__ W,
               const float* __restrict__ gamma,
               const float* __restrict__ beta,
               const float* __restrict__ rmean,
               const float* __restrict__ rvar,
               int* __restrict__ cnt, int* __restrict__ ovf,
               unsigned int* __restrict__ sorted,
               float* __restrict__ out,
               int P, int NBpad, int CAPR) {
    __shared__ int lh[MAXNBP];
    __shared__ int rbase[MAXNBP];
    const int t = threadIdx.x;
    const int r = blockIdx.x & (NREG - 1);   // region ~ XCD (round-robin)

    for (int b = t; b < NBpad; b += SBLK) lh[b] = 0;
    __syncthreads();

    const int base = blockIdx.x * SCHUNK;
    int mm[PPT], rk[PPT];
#pragma unroll
    for (int i = 0; i < PPT; ++i) {
        int p = base + i * SBLK + t;
        mm[i] = (p < P) ? idx[p] : -1;
        rk[i] = (mm[i] >= 0) ? atomicAdd(&lh[mm[i] >> BSHIFT], 1) : 0;
    }
    __syncthreads();

    int* crow = cnt + (size_t)r * NBpad;
    for (int b = t; b < NBpad; b += SBLK) {
        int h = lh[b];
        rbase[b] = h ? atomicAdd(&crow[b], h) : 0;
    }
    __syncthreads();

#pragma unroll
    for (int i = 0; i < PPT; ++i) {
        if (mm[i] < 0) continue;
        int p = base + i * SBLK + t;
        int b = mm[i] >> BSHIFT;
        int slot = rbase[b] + rk[i];
        if (slot < CAPR) {
            sorted[((size_t)b * NREG + r) * CAPR + slot] =
                (unsigned)p | ((unsigned)(mm[i] & (BPILL - 1)) << 24);
        } else {
            fallback_point(p, mm[i], gf, W, gamma, beta, rmean, rvar, out, ovf);
        }
    }
}

// ---------- K2: pool — R8 structure: static grid, 64-token gather, MFMA -----
__global__ __launch_bounds__(PBLK, 8)
void k_pool(const float* __restrict__ gf,
            const unsigned int* __restrict__ sorted,
            const int* __restrict__ cnt,
            const int* __restrict__ ovf,
            const float* __restrict__ W,
            const float* __restrict__ gamma,
            const float* __restrict__ beta,
            const float* __restrict__ rmean,
            const float* __restrict__ rvar,
            float* __restrict__ out, int M, int NBpad, int CAPR) {
    __shared__ unsigned int acc[129 * 65];   // stride 65; row 128 = trash (SENT)
    const int t = threadIdx.x;
    const int lane = t & 63;
    const int wv = t >> 6;                   // wave == region 0..7
    const int n = lane & 15;
    const int q = lane >> 4;

    for (int i = t; i < 129 * 65; i += PBLK) acc[i] = 0u;

    // B fragments: W rows k>=10 zeroed -> A K-padding free
    half8 bfrag[4];
    float inv[4], bia[4];
#pragma unroll
    for (int tt = 0; tt < 4; ++tt) {
        int c = tt * 16 + n;
#pragma unroll
        for (int j = 0; j < 8; ++j) {
            int k = q * 8 + j;
            bfrag[tt][j] = (k < C_IN) ? (_Float16)W[k * C_OUT + c] : (_Float16)0.f;
        }
        float is = gamma[c] * rsqrtf(rvar[c] + 1e-3f);
        inv[tt] = is;
        bia[tt] = fmaf(-rmean[c], is, beta[c]);
    }
    __syncthreads();

    const int blk = blockIdx.x;
    const int cn = min(cnt[(size_t)wv * NBpad + blk], CAPR);   // real count
    const unsigned int* src0 = sorted + ((size_t)blk * NREG + wv) * CAPR;
    const float2* gf2 = (const float2*)gf;

    for (int rb = 0; rb < cn; rb += 64) {
        // lane-per-point: full-wave 40B contiguous gather + packed cvt
        unsigned v = (rb + lane < cn) ? src0[rb + lane] : SENT;
        const float2* src = gf2 + (size_t)(v & 0xFFFFFFu) * 5;
        float2 x0 = src[0], x1 = src[1], x2 = src[2], x3 = src[3], x4 = src[4];
        int u0 = __builtin_bit_cast(int, __builtin_amdgcn_cvt_pkrtz(x0.x, x0.y));
        int u1 = __builtin_bit_cast(int, __builtin_amdgcn_cvt_pkrtz(x1.x, x1.y));
        int u2 = __builtin_bit_cast(int, __builtin_amdgcn_cvt_pkrtz(x2.x, x2.y));
        int u3 = __builtin_bit_cast(int, __builtin_amdgcn_cvt_pkrtz(x3.x, x3.y));
        int u4 = __builtin_bit_cast(int, __builtin_amdgcn_cvt_pkrtz(x4.x, x4.y));

        const int ng = min(4, ((cn - rb) + 15) >> 4);   // 16-groups left
#pragma unroll
        for (int g = 0; g < 4; ++g) {
            if (g >= ng) break;              // wave-uniform
            const int sl = (g << 4) + n;     // source lane: point g*16+n
            int b0 = __shfl(u0, sl, 64);
            int b1 = __shfl(u1, sl, 64);
            int b2 = __shfl(u2, sl, 64);
            int b3 = __shfl(u3, sl, 64);
            int b4 = __shfl(u4, sl, 64);
            int4 a32;
            a32.x = (q == 0) ? b0 : ((q == 1) ? b4 : 0);
            a32.y = (q == 0) ? b1 : 0;
            a32.z = (q == 0) ? b2 : 0;
            a32.w = (q == 0) ? b3 : 0;
            half8 a = __builtin_bit_cast(half8, a32);
            f32x4 z = {0.f, 0.f, 0.f, 0.f};
            f32x4 d0 = __builtin_amdgcn_mfma_f32_16x16x32_f16(a, bfrag[0], z, 0, 0, 0);
            f32x4 d1 = __builtin_amdgcn_mfma_f32_16x16x32_f16(a, bfrag[1], z, 0, 0, 0);
            f32x4 d2 = __builtin_amdgcn_mfma_f32_16x16x32_f16(a, bfrag[2], z, 0, 0, 0);
            f32x4 d3 = __builtin_amdgcn_mfma_f32_16x16x32_f16(a, bfrag[3], z, 0, 0, 0);
#pragma unroll
            for (int r = 0; r < 4; ++r) {    // C row = 4q+r = point
                int pv = __shfl((int)v, (g << 4) + (q << 2) + r, 64);
                int abase = (int)(((unsigned)pv) >> 24) * 65 + n;   // ml row
                float h0 = fmaxf(fmaf(d0[r], inv[0], bia[0]), 0.f);
                float h1 = fmaxf(fmaf(d1[r], inv[1], bia[1]), 0.f);
                float h2 = fmaxf(fmaf(d2[r], inv[2], bia[2]), 0.f);
                float h3 = fmaxf(fmaf(d3[r], inv[3], bia[3]), 0.f);
                atomicMax(&acc[abase +  0], __float_as_uint(h0));
                atomicMax(&acc[abase + 16], __float_as_uint(h1));
                atomicMax(&acc[abase + 32], __float_as_uint(h2));
                atomicMax(&acc[abase + 48], __float_as_uint(h3));
            }
        }
    }
    __syncthreads();

    // coalesced writeback of 128 pillars x 64 channels; merge if overflow ran
    const int anyovf = ovf[0];
    const int mbase = blk * BPILL;
#pragma unroll
    for (int i = 0; i < (BPILL * C_OUT) / PBLK; ++i) {
        int wdx = i * PBLK + t;
        int row = wdx >> 6, c = wdx & 63;
        int m = mbase + row;
        if (m < M) {
            unsigned uv = acc[row * 65 + c];
            if (anyovf) atomicMax((unsigned*)out + (size_t)m * C_OUT + c, uv);
            else        out[(size_t)m * C_OUT + c] = __uint_as_float(uv);
        }
    }
}

extern "C" void kernel_launch(void* const* d_in, const int* in_sizes, int n_in,
                              void* d_out, int out_size, void* d_ws, size_t ws_size,
                              hipStream_t stream) {
    const float* gf    = (const float*)d_in[0];
    const int*   idx   = (const int*)  d_in[1];
    const float* W     = (const float*)d_in[3];
    const float* gamma = (const float*)d_in[4];
    const float* beta  = (const float*)d_in[5];
    const float* rmean = (const float*)d_in[6];
    const float* rvar  = (const float*)d_in[7];
    float*       out   = (float*)d_out;

    const int P  = in_sizes[0] / C_IN;
    const int M  = out_size / C_OUT;
    const int NB    = (M + BPILL - 1) >> BSHIFT;    // 1563 for M=200k
    const int NBpad = (NB + 32) & ~31;              // 1568
    const int E     = NREG * NBpad;                 // 12544 cells
    const int NSB   = (P + SCHUNK - 1) / SCHUNK;    // 489

    char* ws = (char*)d_ws;
    auto align256 = [](size_t x) { return (x + 255) & ~(size_t)255; };
    int* cnt = (int*)ws;  ws += align256((size_t)E * 4);
    int* ovf = (int*)ws;  ws += 256;
    unsigned int* sorted = (unsigned int*)ws;

    // capacity per (bucket,region) cell; shrink if workspace is small
    int CAPR = 512;                                  // cell mean ~160, max ~220
    size_t fixed = (size_t)((char*)sorted - (char*)cnt);
    while (CAPR > 128 && fixed + (size_t)E * CAPR * 4 > ws_size) CAPR -= 128;

    hipMemsetAsync(cnt, 0, fixed, stream);           // cnt + ovf in one memset

    k_scatter<<<NSB, SBLK, 0, stream>>>(idx, gf, W, gamma, beta, rmean, rvar,
                                        cnt, ovf, sorted, out, P, NBpad, CAPR);
    k_pool   <<<NB,  PBLK, 0, stream>>>(gf, sorted, cnt, ovf, W, gamma, beta,
                                        rmean, rvar, out, M, NBpad, CAPR);
}